// Round 1
// baseline (1396.176 us; speedup 1.0000x reference)
//
#include <hip/hip_runtime.h>
#include <math.h>

// Problem constants
#define BATCH 4
#define SEQ   2048
#define DMODEL 1024

#define BM 64
#define BN 64
#define BK 16

// C[M,N] = (A @ B(^T) + bias) * scale, optionally writing C transposed (C[n*M+m]).
// A: [M,K] row-major. B: [K,N] if !TRANS_B, [N,K] if TRANS_B (computes A@B^T).
// bias: [M,N] or nullptr (shared across batch). Batched via blockIdx.z strides.
template<bool TRANS_B, bool TRANS_OUT>
__global__ __launch_bounds__(256)
void gemm_kernel(const float* __restrict__ A, const float* __restrict__ B,
                 const float* __restrict__ bias, float* __restrict__ C,
                 int M, int N, int K, float scale,
                 long sAb, long sBb, long sCb)
{
    const int bx = blockIdx.x, by = blockIdx.y, bz = blockIdx.z;
    A += (long)bz * sAb;
    B += (long)bz * sBb;
    C += (long)bz * sCb;

    const int tid = threadIdx.x;       // 0..255
    const int tx = tid & 15;           // 0..15 -> N direction
    const int ty = tid >> 4;           // 0..15 -> M direction
    const int row0 = by * BM;
    const int col0 = bx * BN;

    __shared__ float As[BK][BM];
    __shared__ float Bs[BK][BN];

    float acc[4][4] = {};

    for (int k0 = 0; k0 < K; k0 += BK) {
        // ---- stage A tile: 64 rows x 16 k, each thread loads a float4 along k
        {
            const int m  = tid >> 2;          // 0..63
            const int kk = (tid & 3) * 4;     // 0,4,8,12
            const float4 va = *(const float4*)(A + (long)(row0 + m) * K + k0 + kk);
            As[kk + 0][m] = va.x;
            As[kk + 1][m] = va.y;
            As[kk + 2][m] = va.z;
            As[kk + 3][m] = va.w;
        }
        // ---- stage B tile
        if (TRANS_B) {
            const int n  = tid >> 2;          // 0..63
            const int kk = (tid & 3) * 4;
            const float4 vb = *(const float4*)(B + (long)(col0 + n) * K + k0 + kk);
            Bs[kk + 0][n] = vb.x;
            Bs[kk + 1][n] = vb.y;
            Bs[kk + 2][n] = vb.z;
            Bs[kk + 3][n] = vb.w;
        } else {
            const int kk = tid >> 4;          // 0..15
            const int n  = (tid & 15) * 4;
            const float4 vb = *(const float4*)(B + (long)(k0 + kk) * N + col0 + n);
            *(float4*)&Bs[kk][n] = vb;
        }
        __syncthreads();

        #pragma unroll
        for (int k = 0; k < BK; ++k) {
            float a[4], b[4];
            *(float4*)a = *(const float4*)&As[k][ty * 4];
            *(float4*)b = *(const float4*)&Bs[k][tx * 4];
            #pragma unroll
            for (int i = 0; i < 4; ++i)
                #pragma unroll
                for (int j = 0; j < 4; ++j)
                    acc[i][j] += a[i] * b[j];
        }
        __syncthreads();
    }

    // ---- epilogue: (+bias) * scale, normal or transposed store
    #pragma unroll
    for (int i = 0; i < 4; ++i) {
        const int m = row0 + ty * 4 + i;
        #pragma unroll
        for (int j = 0; j < 4; ++j) {
            const int n = col0 + tx * 4 + j;
            float val = acc[i][j];
            if (bias) val += bias[(long)m * N + n];
            val *= scale;
            if (TRANS_OUT)
                C[(long)n * M + m] = val;
            else
                C[(long)m * N + n] = val;
        }
    }
}

// In-place row softmax: one block per row of length SEQ (2048), 256 threads.
__global__ __launch_bounds__(256)
void softmax_kernel(float* __restrict__ data)
{
    const long row = blockIdx.x;
    float* p = data + row * (long)SEQ;
    const int tid = threadIdx.x;
    const int PER = SEQ / 256;  // 8

    float v[PER];
    float m = -1e30f;
    #pragma unroll
    for (int i = 0; i < PER; ++i) {
        v[i] = p[tid + i * 256];
        m = fmaxf(m, v[i]);
    }

    __shared__ float red[256];
    red[tid] = m;
    __syncthreads();
    #pragma unroll
    for (int s = 128; s > 0; s >>= 1) {
        if (tid < s) red[tid] = fmaxf(red[tid], red[tid + s]);
        __syncthreads();
    }
    m = red[0];
    __syncthreads();

    float sum = 0.f;
    #pragma unroll
    for (int i = 0; i < PER; ++i) {
        v[i] = __expf(v[i] - m);
        sum += v[i];
    }
    red[tid] = sum;
    __syncthreads();
    #pragma unroll
    for (int s = 128; s > 0; s >>= 1) {
        if (tid < s) red[tid] += red[tid + s];
        __syncthreads();
    }
    const float inv = 1.0f / red[0];
    #pragma unroll
    for (int i = 0; i < PER; ++i)
        p[tid + i * 256] = v[i] * inv;
}

extern "C" void kernel_launch(void* const* d_in, const int* in_sizes, int n_in,
                              void* d_out, int out_size, void* d_ws, size_t ws_size,
                              hipStream_t stream)
{
    const float* q  = (const float*)d_in[0];   // [4, 2048, 1024]
    const float* k  = (const float*)d_in[1];   // [4, 2048, 1024]
    const float* v  = (const float*)d_in[2];   // [4, 2048, 1024]
    const float* pe = (const float*)d_in[3];   // [10000, 1024] (use first 2048 rows)
    const float* Uq = (const float*)d_in[4];   // [1024, 1024]
    const float* Uk = (const float*)d_in[5];   // [1024, 1024]

    float* out      = (float*)d_out;
    float* ctx_out  = out;                                   // [4][1024][2048] = context^T per batch
    float* attn_out = out + (long)BATCH * SEQ * DMODEL;      // [4][2048][2048]

    float* qpe   = (float*)d_ws;                             // [2048, 1024]
    float* kpe   = qpe + (long)SEQ * DMODEL;                 // [2048, 1024]
    float* biasM = kpe + (long)SEQ * DMODEL;                 // [2048, 2048]

    const float inv_scale = 1.0f / sqrtf(128.0f);            // 1/sqrt(2*d_k)

    dim3 blk(256);

    // qpe = pe[:S] @ Uq ; kpe = pe[:S] @ Uk
    gemm_kernel<false, false><<<dim3(DMODEL / BN, SEQ / BM, 1), blk, 0, stream>>>(
        pe, Uq, nullptr, qpe, SEQ, DMODEL, DMODEL, 1.0f, 0, 0, 0);
    gemm_kernel<false, false><<<dim3(DMODEL / BN, SEQ / BM, 1), blk, 0, stream>>>(
        pe, Uk, nullptr, kpe, SEQ, DMODEL, DMODEL, 1.0f, 0, 0, 0);

    // biasM = qpe @ kpe^T
    gemm_kernel<true, false><<<dim3(SEQ / BN, SEQ / BM, 1), blk, 0, stream>>>(
        qpe, kpe, nullptr, biasM, SEQ, SEQ, DMODEL, 1.0f, 0, 0, 0);

    // attn_out = (q @ k^T + biasM) * inv_scale   (batched over 4)
    gemm_kernel<true, false><<<dim3(SEQ / BN, SEQ / BM, BATCH), blk, 0, stream>>>(
        q, k, biasM, attn_out, SEQ, SEQ, DMODEL, inv_scale,
        (long)SEQ * DMODEL, (long)SEQ * DMODEL, (long)SEQ * SEQ);

    // softmax rows in place (attn stays in d_out as output 1)
    softmax_kernel<<<dim3(BATCH * SEQ), blk, 0, stream>>>(attn_out);

    // ctx_out[b][d][q] = (attn @ v)[b][q][d]   (batched, transposed store)
    gemm_kernel<false, true><<<dim3(DMODEL / BN, SEQ / BM, BATCH), blk, 0, stream>>>(
        attn_out, v, nullptr, ctx_out, SEQ, DMODEL, SEQ, 1.0f,
        (long)SEQ * SEQ, (long)SEQ * DMODEL, (long)DMODEL * SEQ);
}

// Round 2
// 501.182 us; speedup vs baseline: 2.7858x; 2.7858x over previous
//
#include <hip/hip_runtime.h>
#include <hip/hip_bf16.h>
#include <math.h>

#define BATCH 4
#define SEQ   2048
#define DMODEL 1024

typedef __attribute__((ext_vector_type(8))) short bf16x8;
typedef __attribute__((ext_vector_type(4))) float floatx4;

// async 16B/lane global->LDS. lds pointer MUST be wave-uniform; dest = base + lane*16.
__device__ __forceinline__ void async_copy16(const void* g, void* lds) {
    __builtin_amdgcn_global_load_lds(
        reinterpret_cast<const unsigned int __attribute__((address_space(1)))*>(
            reinterpret_cast<unsigned long long>(g)),
        reinterpret_cast<unsigned int __attribute__((address_space(3)))*>(
            (unsigned int)reinterpret_cast<unsigned long long>(lds)),
        16, 0, 0);
}

// C = (A @ B_storage^T + bias) * scale.
// A: [M,K] bf16 row-major. B_storage: [N,K] bf16 (so logical B[k][n] = storage[n][k]).
// SPLIT: A/B given as hi+lo bf16 pairs; computes hi*hi + hi*lo + lo*hi (fp32-class).
// Output: fp32 [M,N], or fp32 [N,M] (OUT_TRANS), or bf16 [M,N] (OUT_BF16).
template<bool SPLIT, bool HAS_BIAS, bool OUT_TRANS, bool OUT_BF16>
__global__ __launch_bounds__(256, 1)
void mfma_gemm(const __hip_bfloat16* __restrict__ Ah, const __hip_bfloat16* __restrict__ Al,
               const __hip_bfloat16* __restrict__ Bh, const __hip_bfloat16* __restrict__ Bl,
               const float* __restrict__ bias, void* __restrict__ Cvoid,
               int M, int N, int K, float scale,
               long sAb, long sBb, long sCb)
{
    constexpr int NBUF = SPLIT ? 2 : 1;
    __shared__ __align__(16) __hip_bfloat16 sA[NBUF][128 * 32];
    __shared__ __align__(16) __hip_bfloat16 sB[NBUF][128 * 32];

    const int bz = blockIdx.z;
    Ah += (long)bz * sAb;
    Bh += (long)bz * sBb;
    if (SPLIT) { Al += (long)bz * sAb; Bl += (long)bz * sBb; }

    const int row0 = blockIdx.y * 128;
    const int col0 = blockIdx.x * 128;
    const int tid  = threadIdx.x;
    const int wave = tid >> 6;
    const int lane = tid & 63;

    // staging: each wave-call moves 16 rows x 32 bf16 (64B/row); lane l -> row l>>2, 16B chunk l&3
    const int srow   = wave * 16 + (lane >> 2);
    const int schunk = (lane & 3) * 8;

    // compute: wave covers 64x64 quadrant, 4x4 grid of 16x16x32 MFMAs
    const int wm = (wave >> 1) * 64;
    const int wn = (wave & 1) * 64;
    const int fr = lane & 15;          // fragment row (m or n)
    const int fk = (lane >> 4) * 8;    // k offset (quad*8)

    const floatx4 zero = {0.f, 0.f, 0.f, 0.f};
    floatx4 acc[4][4];
    #pragma unroll
    for (int i = 0; i < 4; ++i)
        #pragma unroll
        for (int j = 0; j < 4; ++j) acc[i][j] = zero;

    for (int k0 = 0; k0 < K; k0 += 32) {
        #pragma unroll
        for (int t = 0; t < 2; ++t) {
            const long arow = (long)(row0 + t * 64 + srow);
            const long brow = (long)(col0 + t * 64 + srow);
            __hip_bfloat16* dA = &sA[0][(t * 64 + wave * 16) * 32];
            __hip_bfloat16* dB = &sB[0][(t * 64 + wave * 16) * 32];
            async_copy16(Ah + arow * K + k0 + schunk, dA);
            async_copy16(Bh + brow * K + k0 + schunk, dB);
            if (SPLIT) {
                async_copy16(Al + arow * K + k0 + schunk, &sA[NBUF - 1][(t * 64 + wave * 16) * 32]);
                async_copy16(Bl + brow * K + k0 + schunk, &sB[NBUF - 1][(t * 64 + wave * 16) * 32]);
            }
        }
        __syncthreads();

        bf16x8 aH[4], bH[4];
        #pragma unroll
        for (int i = 0; i < 4; ++i) aH[i] = *(const bf16x8*)&sA[0][(wm + i * 16 + fr) * 32 + fk];
        #pragma unroll
        for (int j = 0; j < 4; ++j) bH[j] = *(const bf16x8*)&sB[0][(wn + j * 16 + fr) * 32 + fk];

        if (SPLIT) {
            bf16x8 aL[4], bL[4];
            #pragma unroll
            for (int i = 0; i < 4; ++i) aL[i] = *(const bf16x8*)&sA[NBUF - 1][(wm + i * 16 + fr) * 32 + fk];
            #pragma unroll
            for (int j = 0; j < 4; ++j) bL[j] = *(const bf16x8*)&sB[NBUF - 1][(wn + j * 16 + fr) * 32 + fk];
            #pragma unroll
            for (int i = 0; i < 4; ++i)
                #pragma unroll
                for (int j = 0; j < 4; ++j) {
                    acc[i][j] = __builtin_amdgcn_mfma_f32_16x16x32_bf16(aH[i], bH[j], acc[i][j], 0, 0, 0);
                    acc[i][j] = __builtin_amdgcn_mfma_f32_16x16x32_bf16(aH[i], bL[j], acc[i][j], 0, 0, 0);
                    acc[i][j] = __builtin_amdgcn_mfma_f32_16x16x32_bf16(aL[i], bH[j], acc[i][j], 0, 0, 0);
                }
        } else {
            #pragma unroll
            for (int i = 0; i < 4; ++i)
                #pragma unroll
                for (int j = 0; j < 4; ++j)
                    acc[i][j] = __builtin_amdgcn_mfma_f32_16x16x32_bf16(aH[i], bH[j], acc[i][j], 0, 0, 0);
        }
        __syncthreads();
    }

    // epilogue — C/D layout: col = lane&15, row = (lane>>4)*4 + reg
    float* Cf = (float*)Cvoid + (long)bz * sCb;
    __hip_bfloat16* Cb = (__hip_bfloat16*)Cvoid + (long)bz * sCb;
    #pragma unroll
    for (int i = 0; i < 4; ++i) {
        #pragma unroll
        for (int r = 0; r < 4; ++r) {
            const int row = row0 + wm + i * 16 + (lane >> 4) * 4 + r;
            #pragma unroll
            for (int j = 0; j < 4; ++j) {
                const int col = col0 + wn + j * 16 + (lane & 15);
                float val = acc[i][j][r];
                if (HAS_BIAS) val += bias[(long)row * N + col];
                val *= scale;
                if (OUT_BF16)      Cb[(long)row * N + col] = __float2bfloat16(val);
                else if (OUT_TRANS) Cf[(long)col * M + row] = val;
                else                Cf[(long)row * N + col] = val;
            }
        }
    }
}

// fp32 -> bf16, 4 elems/thread
__global__ __launch_bounds__(256)
void convert_bf16_kernel(const float* __restrict__ in, __hip_bfloat16* __restrict__ out, long n)
{
    const long i = ((long)blockIdx.x * 256 + threadIdx.x) * 4;
    if (i >= n) return;
    float va[4];
    *(float4*)va = *(const float4*)(in + i);
    __align__(8) __hip_bfloat16 h[4];
    #pragma unroll
    for (int j = 0; j < 4; ++j) h[j] = __float2bfloat16(va[j]);
    *(uint2*)(out + i) = *(uint2*)h;
}

// fp32 -> (hi, lo) bf16 pair: hi = bf16(x), lo = bf16(x - float(hi))
__global__ __launch_bounds__(256)
void split_convert_kernel(const float* __restrict__ in, __hip_bfloat16* __restrict__ hi,
                          __hip_bfloat16* __restrict__ lo, long n)
{
    const long i = ((long)blockIdx.x * 256 + threadIdx.x) * 4;
    if (i >= n) return;
    float va[4];
    *(float4*)va = *(const float4*)(in + i);
    __align__(8) __hip_bfloat16 h[4], l[4];
    #pragma unroll
    for (int j = 0; j < 4; ++j) {
        h[j] = __float2bfloat16(va[j]);
        l[j] = __float2bfloat16(va[j] - __bfloat162float(h[j]));
    }
    *(uint2*)(hi + i) = *(uint2*)h;
    *(uint2*)(lo + i) = *(uint2*)l;
}

// in [R][C] fp32 -> out [C][R] bf16 (batched via blockIdx.z)
__global__ __launch_bounds__(256)
void transpose_convert_kernel(const float* __restrict__ in, __hip_bfloat16* __restrict__ out,
                              int R, int C, long sIn, long sOut)
{
    in  += (long)blockIdx.z * sIn;
    out += (long)blockIdx.z * sOut;
    __shared__ float t[32][33];
    const int c0 = blockIdx.x * 32, r0 = blockIdx.y * 32;
    for (int i = threadIdx.y; i < 32; i += 8)
        t[i][threadIdx.x] = in[(long)(r0 + i) * C + c0 + threadIdx.x];
    __syncthreads();
    for (int i = threadIdx.y; i < 32; i += 8)
        out[(long)(c0 + i) * R + r0 + threadIdx.x] = __float2bfloat16(t[threadIdx.x][i]);
}

// in-place row softmax, rows of length SEQ
__global__ __launch_bounds__(256)
void softmax_kernel(float* __restrict__ data)
{
    const long row = blockIdx.x;
    float* p = data + row * (long)SEQ;
    const int tid = threadIdx.x;
    const int PER = SEQ / 256;  // 8

    float v[PER];
    float m = -1e30f;
    #pragma unroll
    for (int i = 0; i < PER; ++i) {
        v[i] = p[tid + i * 256];
        m = fmaxf(m, v[i]);
    }
    __shared__ float red[256];
    red[tid] = m;
    __syncthreads();
    #pragma unroll
    for (int s = 128; s > 0; s >>= 1) {
        if (tid < s) red[tid] = fmaxf(red[tid], red[tid + s]);
        __syncthreads();
    }
    m = red[0];
    __syncthreads();
    float sum = 0.f;
    #pragma unroll
    for (int i = 0; i < PER; ++i) {
        v[i] = __expf(v[i] - m);
        sum += v[i];
    }
    red[tid] = sum;
    __syncthreads();
    #pragma unroll
    for (int s = 128; s > 0; s >>= 1) {
        if (tid < s) red[tid] += red[tid + s];
        __syncthreads();
    }
    const float inv = 1.0f / red[0];
    #pragma unroll
    for (int i = 0; i < PER; ++i)
        p[tid + i * 256] = v[i] * inv;
}

extern "C" void kernel_launch(void* const* d_in, const int* in_sizes, int n_in,
                              void* d_out, int out_size, void* d_ws, size_t ws_size,
                              hipStream_t stream)
{
    const float* q  = (const float*)d_in[0];   // [4, 2048, 1024]
    const float* k  = (const float*)d_in[1];
    const float* v  = (const float*)d_in[2];
    const float* pe = (const float*)d_in[3];   // [10000, 1024], first 2048 rows used
    const float* Uq = (const float*)d_in[4];   // [1024, 1024] (x @ Uq)
    const float* Uk = (const float*)d_in[5];

    float* out      = (float*)d_out;
    float* ctx_out  = out;                                   // [4][1024][2048] (context^T per batch)
    float* attn_out = out + (long)BATCH * SEQ * DMODEL;      // [4][2048][2048]

    const long SD = (long)BATCH * SEQ * DMODEL;   // 8.4M elems
    char* w = (char*)d_ws;
    __hip_bfloat16* q_hi  = (__hip_bfloat16*)w;  w += SD * 2;
    __hip_bfloat16* q_lo  = (__hip_bfloat16*)w;  w += SD * 2;
    __hip_bfloat16* k_hi  = (__hip_bfloat16*)w;  w += SD * 2;
    __hip_bfloat16* k_lo  = (__hip_bfloat16*)w;  w += SD * 2;
    __hip_bfloat16* pe_bf = (__hip_bfloat16*)w;  w += (long)SEQ * DMODEL * 2;
    __hip_bfloat16* UqT   = (__hip_bfloat16*)w;  w += (long)DMODEL * DMODEL * 2;
    __hip_bfloat16* UkT   = (__hip_bfloat16*)w;  w += (long)DMODEL * DMODEL * 2;
    __hip_bfloat16* qpe_bf= (__hip_bfloat16*)w;  w += (long)SEQ * DMODEL * 2;
    __hip_bfloat16* kpe_bf= (__hip_bfloat16*)w;  w += (long)SEQ * DMODEL * 2;
    float*          biasM = (float*)w;           w += (long)SEQ * SEQ * 4;
    // aliases (lifetimes disjoint, stream-ordered):
    __hip_bfloat16* attn_bf = q_hi;   // needs 16.8M elems = q_hi+q_lo region; used after scores GEMM
    __hip_bfloat16* vT      = k_hi;   // needs 8.4M elems = k_hi region; used after scores GEMM

    const float inv_scale = 1.0f / sqrtf(128.0f);

    // --- conversions
    convert_bf16_kernel<<<dim3((SEQ * DMODEL) / 4 / 256), 256, 0, stream>>>(pe, pe_bf, (long)SEQ * DMODEL);
    transpose_convert_kernel<<<dim3(DMODEL / 32, DMODEL / 32, 1), dim3(32, 8), 0, stream>>>(
        Uq, UqT, DMODEL, DMODEL, 0, 0);
    transpose_convert_kernel<<<dim3(DMODEL / 32, DMODEL / 32, 1), dim3(32, 8), 0, stream>>>(
        Uk, UkT, DMODEL, DMODEL, 0, 0);
    split_convert_kernel<<<dim3(SD / 4 / 256), 256, 0, stream>>>(q, q_hi, q_lo, SD);
    split_convert_kernel<<<dim3(SD / 4 / 256), 256, 0, stream>>>(k, k_hi, k_lo, SD);

    // --- qpe = pe @ Uq, kpe = pe @ Uk  (bf16 out)
    mfma_gemm<false, false, false, true><<<dim3(DMODEL / 128, SEQ / 128, 1), 256, 0, stream>>>(
        pe_bf, nullptr, UqT, nullptr, nullptr, qpe_bf, SEQ, DMODEL, DMODEL, 1.0f, 0, 0, 0);
    mfma_gemm<false, false, false, true><<<dim3(DMODEL / 128, SEQ / 128, 1), 256, 0, stream>>>(
        pe_bf, nullptr, UkT, nullptr, nullptr, kpe_bf, SEQ, DMODEL, DMODEL, 1.0f, 0, 0, 0);

    // --- biasM = qpe @ kpe^T (fp32)
    mfma_gemm<false, false, false, false><<<dim3(SEQ / 128, SEQ / 128, 1), 256, 0, stream>>>(
        qpe_bf, nullptr, kpe_bf, nullptr, nullptr, biasM, SEQ, SEQ, DMODEL, 1.0f, 0, 0, 0);

    // --- scores = (q @ k^T + biasM) * inv_scale  (split bf16, batched)
    mfma_gemm<true, true, false, false><<<dim3(SEQ / 128, SEQ / 128, BATCH), 256, 0, stream>>>(
        q_hi, q_lo, k_hi, k_lo, biasM, attn_out, SEQ, SEQ, DMODEL, inv_scale,
        (long)SEQ * DMODEL, (long)SEQ * DMODEL, (long)SEQ * SEQ);

    // --- softmax rows in place
    softmax_kernel<<<dim3(BATCH * SEQ), 256, 0, stream>>>(attn_out);

    // --- attn -> bf16 ; v -> v^T bf16
    convert_bf16_kernel<<<dim3((int)((long)BATCH * SEQ * SEQ / 4 / 256)), 256, 0, stream>>>(
        attn_out, attn_bf, (long)BATCH * SEQ * SEQ);
    transpose_convert_kernel<<<dim3(DMODEL / 32, SEQ / 32, BATCH), dim3(32, 8), 0, stream>>>(
        v, vT, SEQ, DMODEL, (long)SEQ * DMODEL, (long)SEQ * DMODEL);

    // --- ctx^T = (attn @ v)^T  (transposed store)
    mfma_gemm<false, false, true, false><<<dim3(DMODEL / 128, SEQ / 128, BATCH), 256, 0, stream>>>(
        attn_bf, nullptr, vT, nullptr, nullptr, ctx_out, SEQ, DMODEL, SEQ, 1.0f,
        (long)SEQ * SEQ, (long)SEQ * DMODEL, (long)SEQ * DMODEL);
}

// Round 3
// 451.975 us; speedup vs baseline: 3.0891x; 1.1089x over previous
//
#include <hip/hip_runtime.h>
#include <hip/hip_bf16.h>
#include <math.h>

#define BATCH 4
#define SEQ   2048
#define DMODEL 1024

typedef __attribute__((ext_vector_type(8))) short bf16x8;
typedef __attribute__((ext_vector_type(4))) float floatx4;

// async 16B/lane global->LDS. lds pointer MUST be wave-uniform; dest = base + lane*16.
__device__ __forceinline__ void async_copy16(const void* g, void* lds) {
    __builtin_amdgcn_global_load_lds(
        reinterpret_cast<const unsigned int __attribute__((address_space(1)))*>(
            reinterpret_cast<unsigned long long>(g)),
        reinterpret_cast<unsigned int __attribute__((address_space(3)))*>(
            (unsigned int)reinterpret_cast<unsigned long long>(lds)),
        16, 0, 0);
}

// C = (A @ B_storage^T + bias) * scale.
// A: [M,K] bf16 row-major. B_storage: [N,K] bf16 (logical B[k][n] = storage[n][k]).
// SPLIT_A: A given as hi+lo bf16 pair; computes (A_hi + A_lo) @ B  (2 MFMAs per tile).
// Output: fp32 [M,N], or fp32 [N,M] (OUT_TRANS), or bf16 [M,N] (OUT_BF16).
template<bool SPLIT_A, bool HAS_BIAS, bool OUT_TRANS, bool OUT_BF16>
__global__ __launch_bounds__(256, 1)
void mfma_gemm(const __hip_bfloat16* __restrict__ Ah, const __hip_bfloat16* __restrict__ Al,
               const __hip_bfloat16* __restrict__ Bh,
               const float* __restrict__ bias, void* __restrict__ Cvoid,
               int M, int N, int K, float scale,
               long sAb, long sBb, long sCb)
{
    constexpr int NA = SPLIT_A ? 2 : 1;
    __shared__ __align__(16) __hip_bfloat16 sA[NA][128 * 32];
    __shared__ __align__(16) __hip_bfloat16 sB[128 * 32];

    const int bz = blockIdx.z;
    Ah += (long)bz * sAb;
    Bh += (long)bz * sBb;
    if (SPLIT_A) Al += (long)bz * sAb;

    const int row0 = blockIdx.y * 128;
    const int col0 = blockIdx.x * 128;
    const int tid  = threadIdx.x;
    const int wave = tid >> 6;
    const int lane = tid & 63;

    // staging: each wave-call moves 16 rows x 32 bf16 (64B/row); lane l -> row l>>2, 16B chunk l&3
    const int srow   = wave * 16 + (lane >> 2);
    const int schunk = (lane & 3) * 8;

    // compute: wave covers 64x64 quadrant, 4x4 grid of 16x16x32 MFMAs
    const int wm = (wave >> 1) * 64;
    const int wn = (wave & 1) * 64;
    const int fr = lane & 15;          // fragment row (m or n)
    const int fk = (lane >> 4) * 8;    // k offset (quad*8)

    const floatx4 zero = {0.f, 0.f, 0.f, 0.f};
    floatx4 acc[4][4];
    #pragma unroll
    for (int i = 0; i < 4; ++i)
        #pragma unroll
        for (int j = 0; j < 4; ++j) acc[i][j] = zero;

    for (int k0 = 0; k0 < K; k0 += 32) {
        #pragma unroll
        for (int t = 0; t < 2; ++t) {
            const long arow = (long)(row0 + t * 64 + srow);
            const long brow = (long)(col0 + t * 64 + srow);
            const int  soff = (t * 64 + wave * 16) * 32;
            async_copy16(Ah + arow * K + k0 + schunk, &sA[0][soff]);
            async_copy16(Bh + brow * K + k0 + schunk, &sB[soff]);
            if (SPLIT_A)
                async_copy16(Al + arow * K + k0 + schunk, &sA[NA - 1][soff]);
        }
        __syncthreads();

        bf16x8 aH[4], bH[4];
        #pragma unroll
        for (int i = 0; i < 4; ++i) aH[i] = *(const bf16x8*)&sA[0][(wm + i * 16 + fr) * 32 + fk];
        #pragma unroll
        for (int j = 0; j < 4; ++j) bH[j] = *(const bf16x8*)&sB[(wn + j * 16 + fr) * 32 + fk];

        if (SPLIT_A) {
            bf16x8 aL[4];
            #pragma unroll
            for (int i = 0; i < 4; ++i) aL[i] = *(const bf16x8*)&sA[NA - 1][(wm + i * 16 + fr) * 32 + fk];
            #pragma unroll
            for (int i = 0; i < 4; ++i)
                #pragma unroll
                for (int j = 0; j < 4; ++j) {
                    acc[i][j] = __builtin_amdgcn_mfma_f32_16x16x32_bf16(aH[i], bH[j], acc[i][j], 0, 0, 0);
                    acc[i][j] = __builtin_amdgcn_mfma_f32_16x16x32_bf16(aL[i], bH[j], acc[i][j], 0, 0, 0);
                }
        } else {
            #pragma unroll
            for (int i = 0; i < 4; ++i)
                #pragma unroll
                for (int j = 0; j < 4; ++j)
                    acc[i][j] = __builtin_amdgcn_mfma_f32_16x16x32_bf16(aH[i], bH[j], acc[i][j], 0, 0, 0);
        }
        __syncthreads();
    }

    // epilogue — C/D layout: col = lane&15, row = (lane>>4)*4 + reg
    float* Cf = (float*)Cvoid + (long)bz * sCb;
    __hip_bfloat16* Cb = (__hip_bfloat16*)Cvoid + (long)bz * sCb;
    #pragma unroll
    for (int i = 0; i < 4; ++i) {
        #pragma unroll
        for (int r = 0; r < 4; ++r) {
            const int row = row0 + wm + i * 16 + (lane >> 4) * 4 + r;
            #pragma unroll
            for (int j = 0; j < 4; ++j) {
                const int col = col0 + wn + j * 16 + (lane & 15);
                float val = acc[i][j][r];
                if (HAS_BIAS) val += bias[(long)row * N + col];
                val *= scale;
                if (OUT_BF16)       Cb[(long)row * N + col] = __float2bfloat16(val);
                else if (OUT_TRANS) Cf[(long)col * M + row] = val;
                else                Cf[(long)row * N + col] = val;
            }
        }
    }
}

// fp32 -> bf16, 4 elems/thread
__global__ __launch_bounds__(256)
void convert_bf16_kernel(const float* __restrict__ in, __hip_bfloat16* __restrict__ out, long n)
{
    const long i = ((long)blockIdx.x * 256 + threadIdx.x) * 4;
    if (i >= n) return;
    float va[4];
    *(float4*)va = *(const float4*)(in + i);
    __align__(8) __hip_bfloat16 h[4];
    #pragma unroll
    for (int j = 0; j < 4; ++j) h[j] = __float2bfloat16(va[j]);
    *(uint2*)(out + i) = *(uint2*)h;
}

// fp32 -> (hi, lo) bf16 pair: hi = bf16(x), lo = bf16(x - float(hi))
__global__ __launch_bounds__(256)
void split_convert_kernel(const float* __restrict__ in, __hip_bfloat16* __restrict__ hi,
                          __hip_bfloat16* __restrict__ lo, long n)
{
    const long i = ((long)blockIdx.x * 256 + threadIdx.x) * 4;
    if (i >= n) return;
    float va[4];
    *(float4*)va = *(const float4*)(in + i);
    __align__(8) __hip_bfloat16 h[4], l[4];
    #pragma unroll
    for (int j = 0; j < 4; ++j) {
        h[j] = __float2bfloat16(va[j]);
        l[j] = __float2bfloat16(va[j] - __bfloat162float(h[j]));
    }
    *(uint2*)(hi + i) = *(uint2*)h;
    *(uint2*)(lo + i) = *(uint2*)l;
}

// in [R][C] fp32 -> out [C][R] bf16 (batched via blockIdx.z)
__global__ __launch_bounds__(256)
void transpose_convert_kernel(const float* __restrict__ in, __hip_bfloat16* __restrict__ out,
                              int R, int C, long sIn, long sOut)
{
    in  += (long)blockIdx.z * sIn;
    out += (long)blockIdx.z * sOut;
    __shared__ float t[32][33];
    const int c0 = blockIdx.x * 32, r0 = blockIdx.y * 32;
    for (int i = threadIdx.y; i < 32; i += 8)
        t[i][threadIdx.x] = in[(long)(r0 + i) * C + c0 + threadIdx.x];
    __syncthreads();
    for (int i = threadIdx.y; i < 32; i += 8)
        out[(long)(c0 + i) * R + r0 + threadIdx.x] = __float2bfloat16(t[threadIdx.x][i]);
}

// in-place row softmax over rows of length SEQ; also emits bf16 copy.
__global__ __launch_bounds__(256)
void softmax_kernel(float* __restrict__ data, __hip_bfloat16* __restrict__ data_bf)
{
    const long row = blockIdx.x;
    float* p = data + row * (long)SEQ;
    __hip_bfloat16* pb = data_bf + row * (long)SEQ;
    const int tid = threadIdx.x;
    const int PER = SEQ / 256;  // 8

    float v[PER];
    float m = -1e30f;
    #pragma unroll
    for (int i = 0; i < PER; ++i) {
        v[i] = p[tid + i * 256];
        m = fmaxf(m, v[i]);
    }
    __shared__ float red[256];
    red[tid] = m;
    __syncthreads();
    #pragma unroll
    for (int s = 128; s > 0; s >>= 1) {
        if (tid < s) red[tid] = fmaxf(red[tid], red[tid + s]);
        __syncthreads();
    }
    m = red[0];
    __syncthreads();
    float sum = 0.f;
    #pragma unroll
    for (int i = 0; i < PER; ++i) {
        v[i] = __expf(v[i] - m);
        sum += v[i];
    }
    red[tid] = sum;
    __syncthreads();
    #pragma unroll
    for (int s = 128; s > 0; s >>= 1) {
        if (tid < s) red[tid] += red[tid + s];
        __syncthreads();
    }
    const float inv = 1.0f / red[0];
    #pragma unroll
    for (int i = 0; i < PER; ++i) {
        const float a = v[i] * inv;
        p[tid + i * 256]  = a;
        pb[tid + i * 256] = __float2bfloat16(a);
    }
}

extern "C" void kernel_launch(void* const* d_in, const int* in_sizes, int n_in,
                              void* d_out, int out_size, void* d_ws, size_t ws_size,
                              hipStream_t stream)
{
    const float* q  = (const float*)d_in[0];   // [4, 2048, 1024]
    const float* k  = (const float*)d_in[1];
    const float* v  = (const float*)d_in[2];
    const float* pe = (const float*)d_in[3];   // [10000, 1024], first 2048 rows used
    const float* Uq = (const float*)d_in[4];   // [1024, 1024] (x @ Uq)
    const float* Uk = (const float*)d_in[5];

    float* out      = (float*)d_out;
    float* ctx_out  = out;                                   // [4][1024][2048] (context^T per batch)
    float* attn_out = out + (long)BATCH * SEQ * DMODEL;      // [4][2048][2048]

    const long SD = (long)BATCH * SEQ * DMODEL;   // 8.4M elems
    char* w = (char*)d_ws;
    __hip_bfloat16* q_hi  = (__hip_bfloat16*)w;  w += SD * 2;
    __hip_bfloat16* q_lo  = (__hip_bfloat16*)w;  w += SD * 2;
    __hip_bfloat16* k_bf  = (__hip_bfloat16*)w;  w += SD * 2;
    __hip_bfloat16* pe_bf = (__hip_bfloat16*)w;  w += (long)SEQ * DMODEL * 2;
    __hip_bfloat16* UqT   = (__hip_bfloat16*)w;  w += (long)DMODEL * DMODEL * 2;  // UqT/UkT contiguous
    __hip_bfloat16* UkT   = (__hip_bfloat16*)w;  w += (long)DMODEL * DMODEL * 2;
    __hip_bfloat16* qpe_bf= (__hip_bfloat16*)w;  w += (long)SEQ * DMODEL * 2;     // qpe/kpe contiguous
    __hip_bfloat16* kpe_bf= (__hip_bfloat16*)w;  w += (long)SEQ * DMODEL * 2;
    float*          biasM = (float*)w;           w += (long)SEQ * SEQ * 4;
    // aliases (lifetimes disjoint, stream-ordered):
    __hip_bfloat16* attn_bf = q_hi;   // 33.5M elems needed = q_hi+q_lo region; written by softmax
    __hip_bfloat16* vT      = k_bf;   // 8.4M elems = k_bf region; written after scores GEMM

    const float inv_scale = 1.0f / sqrtf(128.0f);

    // --- conversions
    convert_bf16_kernel<<<dim3((SEQ * DMODEL) / 4 / 256), 256, 0, stream>>>(pe, pe_bf, (long)SEQ * DMODEL);
    transpose_convert_kernel<<<dim3(DMODEL / 32, DMODEL / 32, 1), dim3(32, 8), 0, stream>>>(
        Uq, UqT, DMODEL, DMODEL, 0, 0);
    transpose_convert_kernel<<<dim3(DMODEL / 32, DMODEL / 32, 1), dim3(32, 8), 0, stream>>>(
        Uk, UkT, DMODEL, DMODEL, 0, 0);
    split_convert_kernel<<<dim3(SD / 4 / 256), 256, 0, stream>>>(q, q_hi, q_lo, SD);
    convert_bf16_kernel<<<dim3(SD / 4 / 256), 256, 0, stream>>>(k, k_bf, SD);

    // --- qpe = pe @ Uq, kpe = pe @ Uk  (one batched launch, bf16 out)
    mfma_gemm<false, false, false, true><<<dim3(DMODEL / 128, SEQ / 128, 2), 256, 0, stream>>>(
        pe_bf, nullptr, UqT, nullptr, qpe_bf, SEQ, DMODEL, DMODEL, 1.0f,
        0, (long)DMODEL * DMODEL, (long)SEQ * DMODEL);

    // --- biasM = qpe @ kpe^T (fp32)
    mfma_gemm<false, false, false, false><<<dim3(SEQ / 128, SEQ / 128, 1), 256, 0, stream>>>(
        qpe_bf, nullptr, kpe_bf, nullptr, biasM, SEQ, SEQ, DMODEL, 1.0f, 0, 0, 0);

    // --- scores = ((q_hi+q_lo) @ k_bf^T + biasM) * inv_scale  (split-A, batched)
    mfma_gemm<true, true, false, false><<<dim3(SEQ / 128, SEQ / 128, BATCH), 256, 0, stream>>>(
        q_hi, q_lo, k_bf, biasM, attn_out, SEQ, SEQ, DMODEL, inv_scale,
        (long)SEQ * DMODEL, (long)SEQ * DMODEL, (long)SEQ * SEQ);

    // --- softmax rows in place + fused bf16 emit
    softmax_kernel<<<dim3(BATCH * SEQ), 256, 0, stream>>>(attn_out, attn_bf);

    // --- v -> v^T bf16
    transpose_convert_kernel<<<dim3(DMODEL / 32, SEQ / 32, BATCH), dim3(32, 8), 0, stream>>>(
        v, vT, SEQ, DMODEL, (long)SEQ * DMODEL, (long)SEQ * DMODEL);

    // --- ctx^T = (attn @ v)^T  (transposed store)
    mfma_gemm<false, false, true, false><<<dim3(DMODEL / 128, SEQ / 128, BATCH), 256, 0, stream>>>(
        attn_bf, nullptr, vT, nullptr, ctx_out, SEQ, DMODEL, SEQ, 1.0f,
        (long)SEQ * SEQ, (long)SEQ * DMODEL, (long)SEQ * DMODEL);
}